// Round 3
// baseline (24.346 us; speedup 1.0000x reference)
//
#include <hip/hip_runtime.h>
#include <hip/hip_bf16.h>

// PSRoIAlign: features [B, C=D*G*G, H, W] fp32, rois [N,5] (b, x1,y1,x2,y2 in
// image coords), output [N, D, G, G] fp32. G=7, SR=2, D=10 for this problem.
//
// Round 3: channel-major mapping. blockIdx.x = channel plane c (490 planes);
// a block's threads cover (64 ROIs x 4 samples) all gathering from ONE
// ~102 KB plane -> L1/L2-resident instead of scattering across 100 MB.

#define G 7
#define SR 2
#define D_OUT 10
#define ROIS_PER_BLOCK 64

__global__ void psroi_align_kernel(const float* __restrict__ rois,
                                   const float* __restrict__ feat,
                                   const int* __restrict__ stride_p,
                                   int N, int B, int C, int H, int W,
                                   float* __restrict__ out) {
    // channel for this block (uniform -> scalar regs)
    int c  = blockIdx.x;
    int ph = (c / G) % G;
    int pw = c % G;

    int t = threadIdx.x;
    int s = t & 3;                 // sample id: iy = s>>1, ix = s&1
    int r = blockIdx.y * ROIS_PER_BLOCK + (t >> 2);
    if (r >= N) return;
    int iy = s >> 1;
    int ix = s & 1;

    // stride may arrive as int32 or float32 bits; disambiguate.
    int iv = stride_p[0];
    float stride_f;
    if (iv > 0 && iv <= 65536) stride_f = (float)iv;
    else                       stride_f = __int_as_float(iv);
    float spatial_scale = 1.0f / stride_f;

    const float* roi = rois + (size_t)r * 5;
    int   b  = (int)roi[0];
    float sw = roi[1] * spatial_scale - 0.5f;
    float sh = roi[2] * spatial_scale - 0.5f;
    float ew = roi[3] * spatial_scale - 0.5f;
    float eh = roi[4] * spatial_scale - 0.5f;
    float roi_w = fmaxf(ew - sw, 0.1f);
    float roi_h = fmaxf(eh - sh, 0.1f);
    float bin_h = roi_h / (float)G;
    float bin_w = roi_w / (float)G;

    const float* __restrict__ fplane = feat + ((size_t)b * C + c) * (size_t)(H * W);

    // this thread's single bilinear sample
    float y  = sh + ((float)ph + ((float)iy + 0.5f) / (float)SR) * bin_h;
    float x  = sw + ((float)pw + ((float)ix + 0.5f) / (float)SR) * bin_w;
    bool  vy = (y > -1.0f) && (y < (float)H);
    bool  vx = (x > -1.0f) && (x < (float)W);

    float cy = fmaxf(y, 0.0f);
    int  ylo = min((int)floorf(cy), H - 1);
    int  yhi = min(ylo + 1, H - 1);
    float ly = (ylo >= H - 1) ? 0.0f : (cy - (float)ylo);
    float hy = 1.0f - ly;

    float cx = fmaxf(x, 0.0f);
    int  xlo = min((int)floorf(cx), W - 1);
    int  xhi = min(xlo + 1, W - 1);
    float lx = (xlo >= W - 1) ? 0.0f : (cx - (float)xlo);
    float hx = 1.0f - lx;

    float val = 0.0f;
    if (vy && vx) {
        float v00 = fplane[(size_t)ylo * W + xlo];
        float v01 = fplane[(size_t)ylo * W + xhi];
        float v10 = fplane[(size_t)yhi * W + xlo];
        float v11 = fplane[(size_t)yhi * W + xhi];
        val = hy * hx * v00 + hy * lx * v01 + ly * hx * v10 + ly * lx * v11;
    }

    // reduce the 2x2 sample grid across the 4-lane group
    val += __shfl_xor(val, 1);
    val += __shfl_xor(val, 2);
    // out[n, d, ph, pw] = out[r*490 + c] since c = d*49 + ph*7 + pw
    if (s == 0) out[(size_t)r * C + c] = val * (1.0f / (float)(SR * SR));
}

extern "C" void kernel_launch(void* const* d_in, const int* in_sizes, int n_in,
                              void* d_out, int out_size, void* d_ws, size_t ws_size,
                              hipStream_t stream) {
    const float* rois = (const float*)d_in[0];
    const float* feat = (const float*)d_in[1];
    const int*   strd = (const int*)d_in[2];
    float* out = (float*)d_out;

    int N = in_sizes[0] / 5;
    const int C = D_OUT * G * G;   // 490
    const int H = 160, W = 160;
    int B = in_sizes[1] / (C * H * W);

    dim3 grid(C, (N + ROIS_PER_BLOCK - 1) / ROIS_PER_BLOCK, 1);
    dim3 block(ROIS_PER_BLOCK * SR * SR, 1, 1);   // 256
    psroi_align_kernel<<<grid, block, 0, stream>>>(rois, feat, strd, N, B, C, H, W, out);
}